// Round 1
// baseline (262.162 us; speedup 1.0000x reference)
//
#include <hip/hip_runtime.h>
#include <math.h>

// LC_OPE: per-row Fourier outer-product embedding contraction.
// out[n,k] = (1/100) * sum_{i,j} X[n,i]*Y[n,j]*lat[n,k,i*7+j]
// X,Y are 7-term embeddings of x[n,147], x[n,148]; lat = x[n,0:147] as (3,49).

#define RL    149   // floats per input row
#define ROWS  64    // rows per block (64*149*4 = 38144 B LDS, 16B-aligned tiles)
#define BLOCK 256
#define NK    3

__global__ __launch_bounds__(BLOCK)
void ope_kernel(const float* __restrict__ x, float* __restrict__ out, int nrows) {
    __shared__ float tile[ROWS * RL];   // 38144 B
    __shared__ float outs[ROWS * NK];   // 768 B

    const int tid = threadIdx.x;
    const long long row0 = (long long)blockIdx.x * ROWS;
    int vr = nrows - (int)row0;
    if (vr > ROWS) vr = ROWS;
    const int nflt = vr * RL;
    const float* __restrict__ src = x + row0 * RL;

    // Coalesced global -> LDS staging. Full blocks: 2384 float4 / 256 thr.
    // row0*RL*4 bytes: blockIdx * 38144 -> always 16B aligned; float4 path
    // valid whenever the float count is a multiple of 4 (always for vr==64).
    if ((nflt & 3) == 0) {
        const float4* s4 = (const float4*)src;
        float4* d4 = (float4*)tile;
        const int n4 = nflt >> 2;
        for (int i = tid; i < n4; i += BLOCK) d4[i] = s4[i];
    } else {
        for (int i = tid; i < nflt; i += BLOCK) tile[i] = src[i];
    }
    __syncthreads();

    if (tid < vr) {
        const float* __restrict__ row = tile + tid * RL;  // lane-stride 149: 2-way bank alias, free
        const float OMEGA = 1.5707963267948966f;  // pi/2
        const float S2    = 1.4142135623730951f;  // sqrt(2)
        const float t0 = row[147] * OMEGA;
        const float t1 = row[148] * OMEGA;
        float X[7], Y[7];
        X[0] = 1.f; Y[0] = 1.f;
        #pragma unroll
        for (int f = 1; f <= 3; ++f) {
            float s, c;
            __sincosf(t0 * (float)f, &s, &c);
            X[2*f-1] = S2 * c;
            X[2*f]   = S2 * s;
            __sincosf(t1 * (float)f, &s, &c);
            Y[2*f-1] = S2 * c;
            Y[2*f]   = S2 * s;
        }
        float acc0 = 0.f, acc1 = 0.f, acc2 = 0.f;
        #pragma unroll
        for (int i = 0; i < 7; ++i) {
            #pragma unroll
            for (int j = 0; j < 7; ++j) {
                const float p = X[i] * Y[j];
                const int c = i * 7 + j;
                acc0 = fmaf(p, row[c],      acc0);
                acc1 = fmaf(p, row[49 + c], acc1);
                acc2 = fmaf(p, row[98 + c], acc2);
            }
        }
        outs[tid * 3 + 0] = acc0 * 0.01f;
        outs[tid * 3 + 1] = acc1 * 0.01f;
        outs[tid * 3 + 2] = acc2 * 0.01f;
    }
    __syncthreads();

    // Coalesced output burst: vr*3 contiguous floats.
    const int nout = vr * NK;
    float* __restrict__ dst = out + row0 * NK;
    for (int i = tid; i < nout; i += BLOCK) dst[i] = outs[i];
}

extern "C" void kernel_launch(void* const* d_in, const int* in_sizes, int n_in,
                              void* d_out, int out_size, void* d_ws, size_t ws_size,
                              hipStream_t stream) {
    const float* x = (const float*)d_in[0];
    float* out = (float*)d_out;
    const int nrows = in_sizes[0] / RL;
    const int grid = (nrows + ROWS - 1) / ROWS;
    ope_kernel<<<grid, BLOCK, 0, stream>>>(x, out, nrows);
}

// Round 2
// 212.363 us; speedup vs baseline: 1.2345x; 1.2345x over previous
//
#include <hip/hip_runtime.h>
#include <stdint.h>
#include <math.h>

// LC_OPE: per-row Fourier outer-product embedding contraction.
// out[n,k] = (1/100) * sum_{i,j} X[n,i]*Y[n,j]*lat[n,k,i*7+j]
// X,Y are 7-term embeddings of x[n,147], x[n,148]; lat = x[n,0:147] as (3,49).
//
// Memory-bound: 1.192 GB read + 24 MB write. Staging via global_load_lds
// (direct HBM->LDS, no reg round-trip) so all of a block's 37 chunk-loads
// stay in flight until the single vmcnt(0) at the barrier.

#define RL    149   // floats per input row
#define ROWS  64    // rows per block
#define BLOCK 256
#define NK    3
#define TILE_BYTES (ROWS * RL * 4)        // 38144
#define CH16       (TILE_BYTES / 1024)    // 37 full 1024B wave-chunks
// tail: 38144 - 37*1024 = 256 B -> one width-4 wave-instruction (64 x 4B)

typedef const __attribute__((address_space(1))) unsigned int as1_uint;
typedef __attribute__((address_space(3))) unsigned int as3_uint;

__global__ __launch_bounds__(BLOCK)
void ope_kernel(const float* __restrict__ x, float* __restrict__ out, int nrows) {
    __shared__ float tile[ROWS * RL];   // 38144 B -> 4 blocks/CU (LDS-limited)
    __shared__ float outs[ROWS * NK];   // 768 B

    const int tid  = threadIdx.x;
    const int lane = tid & 63;
    const int wid  = tid >> 6;
    const long long row0 = (long long)blockIdx.x * ROWS;
    int vr = nrows - (int)row0;
    if (vr > ROWS) vr = ROWS;

    const char* __restrict__ srcb = (const char*)(x + row0 * RL); // 16B-aligned: 38144*blockIdx
    char* ldsb = (char*)tile;

    if (vr == ROWS) {
        // Async global->LDS: each wave-instruction moves 1024 B (64 lanes x 16 B).
        // LDS dest is wave-uniform base; HW adds lane*16. No VGPR staging, no
        // per-iteration waitcnt -> ~9 loads in flight per wave.
        for (int ci = wid; ci < CH16; ci += 4) {
            __builtin_amdgcn_global_load_lds((as1_uint*)(srcb + ci * 1024 + lane * 16),
                                             (as3_uint*)(ldsb + ci * 1024), 16, 0, 0);
        }
        if (wid == 1) {  // 256 B tail: 64 lanes x 4 B
            __builtin_amdgcn_global_load_lds((as1_uint*)(srcb + CH16 * 1024 + lane * 4),
                                             (as3_uint*)(ldsb + CH16 * 1024), 4, 0, 0);
        }
    } else {
        // partial last block (doesn't occur for N=2e6, defensive)
        const int nflt = vr * RL;
        const float* srcf = (const float*)srcb;
        for (int i = tid; i < nflt; i += BLOCK) tile[i] = srcf[i];
    }
    __syncthreads();   // compiler emits s_waitcnt vmcnt(0) here -> loads drained

    if (tid < vr) {
        const float* __restrict__ row = tile + tid * RL;  // lane-stride 149: 2-way bank alias, free
        const float OMEGA = 1.5707963267948966f;  // pi/2
        const float S2    = 1.4142135623730951f;  // sqrt(2)
        const float t0 = row[147] * OMEGA;
        const float t1 = row[148] * OMEGA;
        float X[7], Y[7];
        X[0] = 1.f; Y[0] = 1.f;
        #pragma unroll
        for (int f = 1; f <= 3; ++f) {
            float s, c;
            __sincosf(t0 * (float)f, &s, &c);
            X[2*f-1] = S2 * c;
            X[2*f]   = S2 * s;
            __sincosf(t1 * (float)f, &s, &c);
            Y[2*f-1] = S2 * c;
            Y[2*f]   = S2 * s;
        }
        float acc0 = 0.f, acc1 = 0.f, acc2 = 0.f;
        #pragma unroll
        for (int i = 0; i < 7; ++i) {
            #pragma unroll
            for (int j = 0; j < 7; ++j) {
                const float p = X[i] * Y[j];
                const int c = i * 7 + j;
                acc0 = fmaf(p, row[c],      acc0);
                acc1 = fmaf(p, row[49 + c], acc1);
                acc2 = fmaf(p, row[98 + c], acc2);
            }
        }
        outs[tid * 3 + 0] = acc0 * 0.01f;
        outs[tid * 3 + 1] = acc1 * 0.01f;
        outs[tid * 3 + 2] = acc2 * 0.01f;
    }
    __syncthreads();

    // Coalesced output burst: vr*3 contiguous floats.
    const int nout = vr * NK;
    float* __restrict__ dst = out + row0 * NK;
    for (int i = tid; i < nout; i += BLOCK) dst[i] = outs[i];
}

extern "C" void kernel_launch(void* const* d_in, const int* in_sizes, int n_in,
                              void* d_out, int out_size, void* d_ws, size_t ws_size,
                              hipStream_t stream) {
    const float* x = (const float*)d_in[0];
    float* out = (float*)d_out;
    const int nrows = in_sizes[0] / RL;
    const int grid = (nrows + ROWS - 1) / ROWS;
    ope_kernel<<<grid, BLOCK, 0, stream>>>(x, out, nrows);
}